// Round 1
// baseline (941.221 us; speedup 1.0000x reference)
//
#include <hip/hip_runtime.h>
#include <cmath>

#define NN 50000
#define KK 15
#define DD 128
#define HH 64
#define NKE (NN * KK)

// ---------------------------------------------------------------------------
// kP: fused 3-segment per-node GEMM, NO LDS, + explicit x ping-pong prefetch.
//   ws[0][row][j] = x[row] @ ew1[0:128]      (XA)
//   ws[1][row][j] = x[row] @ ew1[128:256]    (XB)
//   ws[2][row][j] = x[row] @ dw1[0:128]      (XC)
// Wave = 8 rows x 64 cols (lane=j). x rows are wave-uniform (scalar path);
// each x float4 feeds 12 FMAs. x loads for step i are issued one full
// W-load+FMA phase (~220 cy) before use to hide the cold-stream latency
// (each x row is read exactly once -> always L2/HBM miss).
// ---------------------------------------------------------------------------
__global__ __launch_bounds__(256) void kP(const float* __restrict__ x,
                                          const float* __restrict__ ew1,
                                          const float* __restrict__ dw1,
                                          float* __restrict__ ws) {
    int lane = threadIdx.x & 63;
    int wv = __builtin_amdgcn_readfirstlane((int)(threadIdx.x >> 6));
    int r0 = blockIdx.x * 32 + wv * 8;       // 50000 % 8 == 0: no intra-wave tail
    if (r0 >= NN) return;

    const float* W0 = ew1;
    const float* W1 = ew1 + DD * HH;
    const float* W2 = dw1;
    const float* xw = x + (size_t)r0 * DD;

    float a0[8], a1[8], a2[8];
#pragma unroll
    for (int r = 0; r < 8; ++r) { a0[r] = 0.f; a1[r] = 0.f; a2[r] = 0.f; }

    float4 xA[8], xB[8];
#pragma unroll
    for (int r = 0; r < 8; ++r) xA[r] = *(const float4*)(xw + r * DD);

#define KP_STEP(I4, XB)                                                       \
    {                                                                         \
        float w00 = W0[((I4) * 4 + 0) * HH + lane];                           \
        float w01 = W0[((I4) * 4 + 1) * HH + lane];                           \
        float w02 = W0[((I4) * 4 + 2) * HH + lane];                           \
        float w03 = W0[((I4) * 4 + 3) * HH + lane];                           \
        float w10 = W1[((I4) * 4 + 0) * HH + lane];                           \
        float w11 = W1[((I4) * 4 + 1) * HH + lane];                           \
        float w12 = W1[((I4) * 4 + 2) * HH + lane];                           \
        float w13 = W1[((I4) * 4 + 3) * HH + lane];                           \
        float w20 = W2[((I4) * 4 + 0) * HH + lane];                           \
        float w21 = W2[((I4) * 4 + 1) * HH + lane];                           \
        float w22 = W2[((I4) * 4 + 2) * HH + lane];                           \
        float w23 = W2[((I4) * 4 + 3) * HH + lane];                           \
        _Pragma("unroll") for (int r = 0; r < 8; ++r) {                       \
            float4 xv = XB[r];                                                \
            a0[r] = fmaf(xv.x, w00, a0[r]);                                   \
            a0[r] = fmaf(xv.y, w01, a0[r]);                                   \
            a0[r] = fmaf(xv.z, w02, a0[r]);                                   \
            a0[r] = fmaf(xv.w, w03, a0[r]);                                   \
            a1[r] = fmaf(xv.x, w10, a1[r]);                                   \
            a1[r] = fmaf(xv.y, w11, a1[r]);                                   \
            a1[r] = fmaf(xv.z, w12, a1[r]);                                   \
            a1[r] = fmaf(xv.w, w13, a1[r]);                                   \
            a2[r] = fmaf(xv.x, w20, a2[r]);                                   \
            a2[r] = fmaf(xv.y, w21, a2[r]);                                   \
            a2[r] = fmaf(xv.z, w22, a2[r]);                                   \
            a2[r] = fmaf(xv.w, w23, a2[r]);                                   \
        }                                                                     \
    }

#pragma unroll 1
    for (int i2 = 0; i2 < 16; ++i2) {
        int i4a = 2 * i2;
        int i4b = 2 * i2 + 1;
        int i4n = (i4b + 1 < 32) ? (i4b + 1) : i4b;   // tail: harmless reload
#pragma unroll
        for (int r = 0; r < 8; ++r)
            xB[r] = *(const float4*)(xw + r * DD + i4b * 4);
        KP_STEP(i4a, xA);
#pragma unroll
        for (int r = 0; r < 8; ++r)
            xA[r] = *(const float4*)(xw + r * DD + i4n * 4);
        KP_STEP(i4b, xB);
    }
#undef KP_STEP

    float* o0 = ws + (size_t)r0 * HH + lane;
    float* o1 = ws + (size_t)NN * HH + (size_t)r0 * HH + lane;
    float* o2 = ws + 2 * (size_t)NN * HH + (size_t)r0 * HH + lane;
#pragma unroll
    for (int r = 0; r < 8; ++r) {
        o0[r * HH] = a0[r];
        o1[r * HH] = a1[r];
        o2[r * HH] = a2[r];
    }
}

// ---------------------------------------------------------------------------
// kE: TWO threads per edge (adjacent lanes), each owns 32 of the 64 hidden-j.
// Lane pair reads identical A/B addresses -> HW-coalesced, FETCH unchanged.
// acc[32] instead of acc[64] halves the register footprint -> ~6 waves/SIMD
// (was 4 at 44% occupancy) to hide the random-B L2/L3-miss latency.
// Layer-1 h duplicated in the pair (~6% extra VALU). Layer-3 partial sums
// reduced with one __shfl_xor(.,1).
// ---------------------------------------------------------------------------
__global__ __launch_bounds__(128, 6) void kE(const int* __restrict__ srcIdx,
                                             const float* __restrict__ dist,
                                             const float* __restrict__ ws,
                                             const float* __restrict__ ew1,
                                             const float* __restrict__ eb1,
                                             const float* __restrict__ ew2,
                                             const float* __restrict__ eb2,
                                             const float* __restrict__ ew3,
                                             const float* __restrict__ eb3,
                                             float* __restrict__ energy_out) {
    int t = blockIdx.x * 128 + threadIdx.x;
    int e = t >> 1;
    int jh = t & 1;
    if (e >= NKE) return;
    int s = srcIdx[e];
    int d = e / KK;
    float dd = dist[e];
    const float* A = ws + (size_t)d * HH;
    const float* B = ws + (size_t)NN * HH + (size_t)s * HH;
    const float* w1l = ew1 + 2 * DD * HH;
    const float* W2 = ew2 + jh * 32;            // this thread's 32-col slice

    float acc[32];
#pragma unroll
    for (int j = 0; j < 32; ++j) acc[j] = 0.f;

    float4 a4 = *(const float4*)A;
    float4 b4 = *(const float4*)B;
#pragma unroll 1
    for (int i4 = 0; i4 < HH / 4; ++i4) {
        float4 a = a4, b = b4;
        int nx = (i4 + 1 < HH / 4) ? (i4 + 1) : i4;
        a4 = *(const float4*)(A + nx * 4);
        b4 = *(const float4*)(B + nx * 4);
        float h[4];
        h[0] = fmaxf(a.x + b.x + dd * w1l[i4 * 4 + 0] + eb1[i4 * 4 + 0], 0.f);
        h[1] = fmaxf(a.y + b.y + dd * w1l[i4 * 4 + 1] + eb1[i4 * 4 + 1], 0.f);
        h[2] = fmaxf(a.z + b.z + dd * w1l[i4 * 4 + 2] + eb1[i4 * 4 + 2], 0.f);
        h[3] = fmaxf(a.w + b.w + dd * w1l[i4 * 4 + 3] + eb1[i4 * 4 + 3], 0.f);
#pragma unroll
        for (int k = 0; k < 4; ++k) {
            const float* wr = W2 + (i4 * 4 + k) * HH;
#pragma unroll
            for (int j4 = 0; j4 < 8; ++j4) {
                float4 w = *(const float4*)(wr + j4 * 4);
                acc[j4 * 4 + 0] = fmaf(h[k], w.x, acc[j4 * 4 + 0]);
                acc[j4 * 4 + 1] = fmaf(h[k], w.y, acc[j4 * 4 + 1]);
                acc[j4 * 4 + 2] = fmaf(h[k], w.z, acc[j4 * 4 + 2]);
                acc[j4 * 4 + 3] = fmaf(h[k], w.w, acc[j4 * 4 + 3]);
            }
        }
    }
    float lg = 0.f;
#pragma unroll
    for (int j = 0; j < 32; ++j)
        lg = fmaf(fmaxf(acc[j] + eb2[jh * 32 + j], 0.f), ew3[jh * 32 + j], lg);
    lg += __shfl_xor(lg, 1);                    // pair reduce: full 64-j sum
    lg += eb3[0];
    if (jh == 0)
        energy_out[e] = 1.f / (1.f + expf(-2.f * lg));
}

// ---------------------------------------------------------------------------
// kF: FOUR threads per node (lanes 4n..4n+3), each owns 16 of 64 hidden-j.
// Was 50000 threads = 3 waves/CU (9% occupancy) with a serial 4096-FMA chain
// -> pure latency-bound. Now 200k threads = 12 waves/CU, acc[16]/thread.
// g (layer-1) duplicated 4x (cheap); kraw reduced via 2x shfl_xor; the
// register-resident sort is duplicated in all 4 lanes (no divergence) and
// the scatter-writes are striped by rank%4.
// ---------------------------------------------------------------------------
__global__ __launch_bounds__(256, 3) void kF(const float* __restrict__ ws,
                                             const float* __restrict__ dw1,
                                             const float* __restrict__ db1,
                                             const float* __restrict__ dw2,
                                             const float* __restrict__ db2,
                                             const float* __restrict__ dw3,
                                             const float* __restrict__ db3,
                                             float* __restrict__ out) {
    int t = blockIdx.x * 256 + threadIdx.x;
    int n = t >> 2;
    int p = t & 3;
    if (n >= NN) return;
    const float* energy = out + 2 * (size_t)NKE;

    float ev[KK];
    float dh = 0.f;
#pragma unroll
    for (int j = 0; j < KK; ++j) {
        ev[j] = energy[(size_t)n * KK + j];
        dh += ev[j];
    }

    const float* XC = ws + 2 * (size_t)NN * HH + (size_t)n * HH;
    const float* w1l = dw1 + DD * HH;
    const float* W2 = dw2 + p * 16;             // this thread's 16-col slice

    float acc[16];
#pragma unroll
    for (int j = 0; j < 16; ++j) acc[j] = 0.f;

    float4 c4 = *(const float4*)XC;
#pragma unroll 1
    for (int i4 = 0; i4 < HH / 4; ++i4) {
        float4 c = c4;
        int nx = (i4 + 1 < HH / 4) ? (i4 + 1) : i4;
        c4 = *(const float4*)(XC + nx * 4);
        float cv[4] = {c.x, c.y, c.z, c.w};
#pragma unroll
        for (int m = 0; m < 4; ++m) {
            int k = i4 * 4 + m;
            float g = fmaxf(cv[m] + dh * w1l[k] + db1[k], 0.f);
            const float* wr = W2 + k * HH;
#pragma unroll
            for (int j4 = 0; j4 < 4; ++j4) {
                float4 w = *(const float4*)(wr + j4 * 4);
                acc[j4 * 4 + 0] = fmaf(g, w.x, acc[j4 * 4 + 0]);
                acc[j4 * 4 + 1] = fmaf(g, w.y, acc[j4 * 4 + 1]);
                acc[j4 * 4 + 2] = fmaf(g, w.z, acc[j4 * 4 + 2]);
                acc[j4 * 4 + 3] = fmaf(g, w.w, acc[j4 * 4 + 3]);
            }
        }
    }
    float kp_ = 0.f;
#pragma unroll
    for (int j = 0; j < 16; ++j)
        kp_ = fmaf(fmaxf(acc[j] + db2[p * 16 + j], 0.f), dw3[p * 16 + j], kp_);
    kp_ += __shfl_xor(kp_, 1);
    kp_ += __shfl_xor(kp_, 2);                  // all 4 lanes hold full kraw
    float kraw = kp_ + db3[0];

    float kcont = 2.f + 13.f / (1.f + expf(-kraw));
    if (p == 3) out[3 * (size_t)NKE + n] = kcont;

    // register-resident sort of (energy desc, idx asc), 16-wide network
    // (duplicated in all 4 lanes of the node group — identical result)
    float se[16];
    int si[16];
#pragma unroll
    for (int j = 0; j < KK; ++j) { se[j] = ev[j]; si[j] = j; }
    se[15] = -1.f; si[15] = 15;

#pragma unroll
    for (int pp = 1; pp < 16; pp <<= 1) {
#pragma unroll
        for (int k = pp; k >= 1; k >>= 1) {
#pragma unroll
            for (int j = k & (pp - 1); j + k < 16; j += 2 * k) {
#pragma unroll
                for (int i = 0; i < k; ++i) {
                    int a = i + j, b = i + j + k;
                    if (b < 16 && (a / (2 * pp)) == (b / (2 * pp))) {
                        bool sw = (se[b] > se[a]) ||
                                  (se[b] == se[a] && si[b] < si[a]);
                        float ea = sw ? se[b] : se[a];
                        float eb = sw ? se[a] : se[b];
                        int ia = sw ? si[b] : si[a];
                        int ib = sw ? si[a] : si[b];
                        se[a] = ea; se[b] = eb; si[a] = ia; si[b] = ib;
                    }
                }
            }
        }
    }

    float kint = rintf(kcont);
    kint = fminf(fmaxf(kint, 2.f), 15.f);

    float wsrt[KK];
    float denom = 0.f;
#pragma unroll
    for (int r = 0; r < KK; ++r) {
        float sel = ((float)(r + 1) <= kint) ? 1.f : 0.f;
        float wvv = se[r] * sel;
        wsrt[r] = wvv;
        denom += wvv;
    }
    denom = fmaxf(denom, 1e-12f);

#pragma unroll
    for (int r = 0; r < KK; ++r) {
        if ((r & 3) == p) {                     // stripe writes across the 4 lanes
            float sel = ((float)(r + 1) <= kint) ? 1.f : 0.f;
            int j0 = si[r];
            out[(size_t)NKE + (size_t)n * KK + j0] = sel;     // edge_gate
            out[(size_t)n * KK + j0] = wsrt[r] / denom;       // edge_weight
        }
    }
}

extern "C" void kernel_launch(void* const* d_in, const int* in_sizes, int n_in,
                              void* d_out, int out_size, void* d_ws, size_t ws_size,
                              hipStream_t stream) {
    const float* x   = (const float*)d_in[0];
    const int*   ei  = (const int*)d_in[1];
    const float* ed  = (const float*)d_in[2];
    const float* ew1 = (const float*)d_in[3];
    const float* eb1 = (const float*)d_in[4];
    const float* ew2 = (const float*)d_in[5];
    const float* eb2 = (const float*)d_in[6];
    const float* ew3 = (const float*)d_in[7];
    const float* eb3 = (const float*)d_in[8];
    const float* dw1 = (const float*)d_in[9];
    const float* db1 = (const float*)d_in[10];
    const float* dw2 = (const float*)d_in[11];
    const float* db2 = (const float*)d_in[12];
    const float* dw3 = (const float*)d_in[13];
    const float* db3 = (const float*)d_in[14];
    float* out = (float*)d_out;
    float* ws  = (float*)d_ws;

    hipLaunchKernelGGL(kP, dim3((NN + 31) / 32), dim3(256), 0, stream,
                       x, ew1, dw1, ws);
    hipLaunchKernelGGL(kE, dim3((2 * NKE + 127) / 128), dim3(128), 0, stream,
                       ei, ed, ws, ew1, eb1, ew2, eb2, ew3, eb3,
                       out + 2 * (size_t)NKE);
    hipLaunchKernelGGL(kF, dim3((4 * NN + 255) / 256), dim3(128 * 2), 0, stream,
                       ws, dw1, db1, dw2, db2, dw3, db3, out);
}

// Round 2
// 912.955 us; speedup vs baseline: 1.0310x; 1.0310x over previous
//
#include <hip/hip_runtime.h>
#include <cmath>

#define NN 50000
#define KK 15
#define DD 128
#define HH 64
#define NKE (NN * KK)

// ---------------------------------------------------------------------------
// kP: fused 3-segment per-node GEMM, NO LDS.  (R0 version, verified.)
//   ws[0][row][j] = x[row] @ ew1[0:128]      (XA)
//   ws[1][row][j] = x[row] @ ew1[128:256]    (XB)
//   ws[2][row][j] = x[row] @ dw1[0:128]      (XC)
// Wave = 8 rows x 64 cols (lane=j).  x read with wave-uniform addresses.
// NOTE (R1 lesson): do NOT add register ping-pong buffers here — xA/xB[8]
// float4 arrays blew the allocator into a 37 GB scratch spill-storm (41 ms).
// ---------------------------------------------------------------------------
__global__ __launch_bounds__(256) void kP(const float* __restrict__ x,
                                          const float* __restrict__ ew1,
                                          const float* __restrict__ dw1,
                                          float* __restrict__ ws) {
    int lane = threadIdx.x & 63;
    int wv = __builtin_amdgcn_readfirstlane((int)(threadIdx.x >> 6));
    int r0 = blockIdx.x * 32 + wv * 8;       // 50000 % 8 == 0: no intra-wave tail
    if (r0 >= NN) return;

    const float* W0 = ew1;
    const float* W1 = ew1 + DD * HH;
    const float* W2 = dw1;
    const float* xw = x + (size_t)r0 * DD;

    float a0[8], a1[8], a2[8];
#pragma unroll
    for (int r = 0; r < 8; ++r) { a0[r] = 0.f; a1[r] = 0.f; a2[r] = 0.f; }

#pragma unroll 1
    for (int i4 = 0; i4 < DD / 4; ++i4) {
        // 12 lane-coalesced W loads (3 segs x 4 rows of W)
        float w00 = W0[(i4 * 4 + 0) * HH + lane];
        float w01 = W0[(i4 * 4 + 1) * HH + lane];
        float w02 = W0[(i4 * 4 + 2) * HH + lane];
        float w03 = W0[(i4 * 4 + 3) * HH + lane];
        float w10 = W1[(i4 * 4 + 0) * HH + lane];
        float w11 = W1[(i4 * 4 + 1) * HH + lane];
        float w12 = W1[(i4 * 4 + 2) * HH + lane];
        float w13 = W1[(i4 * 4 + 3) * HH + lane];
        float w20 = W2[(i4 * 4 + 0) * HH + lane];
        float w21 = W2[(i4 * 4 + 1) * HH + lane];
        float w22 = W2[(i4 * 4 + 2) * HH + lane];
        float w23 = W2[(i4 * 4 + 3) * HH + lane];
#pragma unroll
        for (int r = 0; r < 8; ++r) {
            // wave-uniform address -> scalar broadcast, no LDS
            float4 xv = *(const float4*)(xw + r * DD + i4 * 4);
            a0[r] = fmaf(xv.x, w00, a0[r]);
            a0[r] = fmaf(xv.y, w01, a0[r]);
            a0[r] = fmaf(xv.z, w02, a0[r]);
            a0[r] = fmaf(xv.w, w03, a0[r]);
            a1[r] = fmaf(xv.x, w10, a1[r]);
            a1[r] = fmaf(xv.y, w11, a1[r]);
            a1[r] = fmaf(xv.z, w12, a1[r]);
            a1[r] = fmaf(xv.w, w13, a1[r]);
            a2[r] = fmaf(xv.x, w20, a2[r]);
            a2[r] = fmaf(xv.y, w21, a2[r]);
            a2[r] = fmaf(xv.z, w22, a2[r]);
            a2[r] = fmaf(xv.w, w23, a2[r]);
        }
    }
    float* o0 = ws + (size_t)r0 * HH + lane;
    float* o1 = ws + (size_t)NN * HH + (size_t)r0 * HH + lane;
    float* o2 = ws + 2 * (size_t)NN * HH + (size_t)r0 * HH + lane;
#pragma unroll
    for (int r = 0; r < 8; ++r) {
        o0[r * HH] = a0[r];
        o1[r * HH] = a1[r];
        o2[r * HH] = a2[r];
    }
}

// ---------------------------------------------------------------------------
// kE: TWO threads per edge (adjacent lanes), each owns 32 of the 64 hidden-j.
// Lane pair reads identical A/B addresses -> HW-coalesced (R1 confirmed:
// hbm_bytes 203->107 MB).  acc[32] halves register state vs acc[64].
// R1 lesson: __launch_bounds__(128,6) caps unified regs at ~84 -> acc
// spilled to scratch (VALUBusy 7%).  Use (128,4): cap 128, need ~70, so
// no spill and occupancy is set by the ACTUAL reg count (~7 waves/SIMD).
// ---------------------------------------------------------------------------
__global__ __launch_bounds__(128, 4) void kE(const int* __restrict__ srcIdx,
                                             const float* __restrict__ dist,
                                             const float* __restrict__ ws,
                                             const float* __restrict__ ew1,
                                             const float* __restrict__ eb1,
                                             const float* __restrict__ ew2,
                                             const float* __restrict__ eb2,
                                             const float* __restrict__ ew3,
                                             const float* __restrict__ eb3,
                                             float* __restrict__ energy_out) {
    int t = blockIdx.x * 128 + threadIdx.x;
    int e = t >> 1;
    int jh = t & 1;
    if (e >= NKE) return;
    int s = srcIdx[e];
    int d = e / KK;
    float dd = dist[e];
    const float* A = ws + (size_t)d * HH;
    const float* B = ws + (size_t)NN * HH + (size_t)s * HH;
    const float* w1l = ew1 + 2 * DD * HH;
    const float* W2 = ew2 + jh * 32;            // this thread's 32-col slice

    float acc[32];
#pragma unroll
    for (int j = 0; j < 32; ++j) acc[j] = 0.f;

    float4 a4 = *(const float4*)A;
    float4 b4 = *(const float4*)B;
#pragma unroll 1
    for (int i4 = 0; i4 < HH / 4; ++i4) {
        float4 a = a4, b = b4;
        int nx = (i4 + 1 < HH / 4) ? (i4 + 1) : i4;
        a4 = *(const float4*)(A + nx * 4);
        b4 = *(const float4*)(B + nx * 4);
        float h[4];
        h[0] = fmaxf(a.x + b.x + dd * w1l[i4 * 4 + 0] + eb1[i4 * 4 + 0], 0.f);
        h[1] = fmaxf(a.y + b.y + dd * w1l[i4 * 4 + 1] + eb1[i4 * 4 + 1], 0.f);
        h[2] = fmaxf(a.z + b.z + dd * w1l[i4 * 4 + 2] + eb1[i4 * 4 + 2], 0.f);
        h[3] = fmaxf(a.w + b.w + dd * w1l[i4 * 4 + 3] + eb1[i4 * 4 + 3], 0.f);
#pragma unroll
        for (int k = 0; k < 4; ++k) {
            const float* wr = W2 + (i4 * 4 + k) * HH;
#pragma unroll
            for (int j4 = 0; j4 < 8; ++j4) {
                float4 w = *(const float4*)(wr + j4 * 4);
                acc[j4 * 4 + 0] = fmaf(h[k], w.x, acc[j4 * 4 + 0]);
                acc[j4 * 4 + 1] = fmaf(h[k], w.y, acc[j4 * 4 + 1]);
                acc[j4 * 4 + 2] = fmaf(h[k], w.z, acc[j4 * 4 + 2]);
                acc[j4 * 4 + 3] = fmaf(h[k], w.w, acc[j4 * 4 + 3]);
            }
        }
    }
    float lg = 0.f;
#pragma unroll
    for (int j = 0; j < 32; ++j)
        lg = fmaf(fmaxf(acc[j] + eb2[jh * 32 + j], 0.f), ew3[jh * 32 + j], lg);
    lg += __shfl_xor(lg, 1);                    // pair reduce: full 64-j sum
    lg += eb3[0];
    if (jh == 0)
        energy_out[e] = 1.f / (1.f + expf(-2.f * lg));
}

// ---------------------------------------------------------------------------
// kF: FOUR threads per node (lanes 4n..4n+3), each owns 16 of 64 hidden-j.
// 200k threads = 12 waves/CU (was 3), acc[16]/thread.  g (layer-1)
// duplicated 4x; kraw reduced via 2x shfl_xor; sort duplicated in all 4
// lanes (no divergence); scatter-writes striped by rank%4.
// (256,3) -> reg cap ~170, need ~80: no spill risk.
// ---------------------------------------------------------------------------
__global__ __launch_bounds__(256, 3) void kF(const float* __restrict__ ws,
                                             const float* __restrict__ dw1,
                                             const float* __restrict__ db1,
                                             const float* __restrict__ dw2,
                                             const float* __restrict__ db2,
                                             const float* __restrict__ dw3,
                                             const float* __restrict__ db3,
                                             float* __restrict__ out) {
    int t = blockIdx.x * 256 + threadIdx.x;
    int n = t >> 2;
    int p = t & 3;
    if (n >= NN) return;
    const float* energy = out + 2 * (size_t)NKE;

    float ev[KK];
    float dh = 0.f;
#pragma unroll
    for (int j = 0; j < KK; ++j) {
        ev[j] = energy[(size_t)n * KK + j];
        dh += ev[j];
    }

    const float* XC = ws + 2 * (size_t)NN * HH + (size_t)n * HH;
    const float* w1l = dw1 + DD * HH;
    const float* W2 = dw2 + p * 16;             // this thread's 16-col slice

    float acc[16];
#pragma unroll
    for (int j = 0; j < 16; ++j) acc[j] = 0.f;

    float4 c4 = *(const float4*)XC;
#pragma unroll 1
    for (int i4 = 0; i4 < HH / 4; ++i4) {
        float4 c = c4;
        int nx = (i4 + 1 < HH / 4) ? (i4 + 1) : i4;
        c4 = *(const float4*)(XC + nx * 4);
        float cv[4] = {c.x, c.y, c.z, c.w};
#pragma unroll
        for (int m = 0; m < 4; ++m) {
            int k = i4 * 4 + m;
            float g = fmaxf(cv[m] + dh * w1l[k] + db1[k], 0.f);
            const float* wr = W2 + k * HH;
#pragma unroll
            for (int j4 = 0; j4 < 4; ++j4) {
                float4 w = *(const float4*)(wr + j4 * 4);
                acc[j4 * 4 + 0] = fmaf(g, w.x, acc[j4 * 4 + 0]);
                acc[j4 * 4 + 1] = fmaf(g, w.y, acc[j4 * 4 + 1]);
                acc[j4 * 4 + 2] = fmaf(g, w.z, acc[j4 * 4 + 2]);
                acc[j4 * 4 + 3] = fmaf(g, w.w, acc[j4 * 4 + 3]);
            }
        }
    }
    float kp_ = 0.f;
#pragma unroll
    for (int j = 0; j < 16; ++j)
        kp_ = fmaf(fmaxf(acc[j] + db2[p * 16 + j], 0.f), dw3[p * 16 + j], kp_);
    kp_ += __shfl_xor(kp_, 1);
    kp_ += __shfl_xor(kp_, 2);                  // all 4 lanes hold full kraw
    float kraw = kp_ + db3[0];

    float kcont = 2.f + 13.f / (1.f + expf(-kraw));
    if (p == 3) out[3 * (size_t)NKE + n] = kcont;

    // register-resident sort of (energy desc, idx asc), 16-wide network
    float se[16];
    int si[16];
#pragma unroll
    for (int j = 0; j < KK; ++j) { se[j] = ev[j]; si[j] = j; }
    se[15] = -1.f; si[15] = 15;

#pragma unroll
    for (int pp = 1; pp < 16; pp <<= 1) {
#pragma unroll
        for (int k = pp; k >= 1; k >>= 1) {
#pragma unroll
            for (int j = k & (pp - 1); j + k < 16; j += 2 * k) {
#pragma unroll
                for (int i = 0; i < k; ++i) {
                    int a = i + j, b = i + j + k;
                    if (b < 16 && (a / (2 * pp)) == (b / (2 * pp))) {
                        bool sw = (se[b] > se[a]) ||
                                  (se[b] == se[a] && si[b] < si[a]);
                        float ea = sw ? se[b] : se[a];
                        float eb = sw ? se[a] : se[b];
                        int ia = sw ? si[b] : si[a];
                        int ib = sw ? si[a] : si[b];
                        se[a] = ea; se[b] = eb; si[a] = ia; si[b] = ib;
                    }
                }
            }
        }
    }

    float kint = rintf(kcont);
    kint = fminf(fmaxf(kint, 2.f), 15.f);

    float wsrt[KK];
    float denom = 0.f;
#pragma unroll
    for (int r = 0; r < KK; ++r) {
        float sel = ((float)(r + 1) <= kint) ? 1.f : 0.f;
        float wvv = se[r] * sel;
        wsrt[r] = wvv;
        denom += wvv;
    }
    denom = fmaxf(denom, 1e-12f);

#pragma unroll
    for (int r = 0; r < KK; ++r) {
        if ((r & 3) == p) {                     // stripe writes across the 4 lanes
            float sel = ((float)(r + 1) <= kint) ? 1.f : 0.f;
            int j0 = si[r];
            out[(size_t)NKE + (size_t)n * KK + j0] = sel;     // edge_gate
            out[(size_t)n * KK + j0] = wsrt[r] / denom;       // edge_weight
        }
    }
}

extern "C" void kernel_launch(void* const* d_in, const int* in_sizes, int n_in,
                              void* d_out, int out_size, void* d_ws, size_t ws_size,
                              hipStream_t stream) {
    const float* x   = (const float*)d_in[0];
    const int*   ei  = (const int*)d_in[1];
    const float* ed  = (const float*)d_in[2];
    const float* ew1 = (const float*)d_in[3];
    const float* eb1 = (const float*)d_in[4];
    const float* ew2 = (const float*)d_in[5];
    const float* eb2 = (const float*)d_in[6];
    const float* ew3 = (const float*)d_in[7];
    const float* eb3 = (const float*)d_in[8];
    const float* dw1 = (const float*)d_in[9];
    const float* db1 = (const float*)d_in[10];
    const float* dw2 = (const float*)d_in[11];
    const float* db2 = (const float*)d_in[12];
    const float* dw3 = (const float*)d_in[13];
    const float* db3 = (const float*)d_in[14];
    float* out = (float*)d_out;
    float* ws  = (float*)d_ws;

    hipLaunchKernelGGL(kP, dim3((NN + 31) / 32), dim3(256), 0, stream,
                       x, ew1, dw1, ws);
    hipLaunchKernelGGL(kE, dim3((2 * NKE + 127) / 128), dim3(128), 0, stream,
                       ei, ed, ws, ew1, eb1, ew2, eb2, ew3, eb3,
                       out + 2 * (size_t)NKE);
    hipLaunchKernelGGL(kF, dim3((4 * NN + 255) / 256), dim3(256), 0, stream,
                       ws, dw1, db1, dw2, db2, dw3, db3, out);
}

// Round 3
// 306.376 us; speedup vs baseline: 3.0721x; 2.9799x over previous
//
#include <hip/hip_runtime.h>
#include <cmath>

#define NN 50000
#define KK 15
#define DD 128
#define HH 64
#define NKE (NN * KK)

// ---------------------------------------------------------------------------
// kP: fused 3-segment per-node GEMM, NO LDS.  (R0 version, verified.)
//   ws[0][row][j] = x[row] @ ew1[0:128]      (XA)
//   ws[1][row][j] = x[row] @ ew1[128:256]    (XB)
//   ws[2][row][j] = x[row] @ dw1[0:128]      (XC)
// Wave = 8 rows x 64 cols (lane=j).  x read with wave-uniform addresses.
// R1 lesson: do NOT add register ping-pong buffers (xA/xB[8] float4 = 64
// live VGPRs -> 37 GB scratch spill storm, 41 ms).
// ---------------------------------------------------------------------------
__global__ __launch_bounds__(256) void kP(const float* __restrict__ x,
                                          const float* __restrict__ ew1,
                                          const float* __restrict__ dw1,
                                          float* __restrict__ ws) {
    int lane = threadIdx.x & 63;
    int wv = __builtin_amdgcn_readfirstlane((int)(threadIdx.x >> 6));
    int r0 = blockIdx.x * 32 + wv * 8;       // 50000 % 8 == 0: no intra-wave tail
    if (r0 >= NN) return;

    const float* W0 = ew1;
    const float* W1 = ew1 + DD * HH;
    const float* W2 = dw1;
    const float* xw = x + (size_t)r0 * DD;

    float a0[8], a1[8], a2[8];
#pragma unroll
    for (int r = 0; r < 8; ++r) { a0[r] = 0.f; a1[r] = 0.f; a2[r] = 0.f; }

#pragma unroll 1
    for (int i4 = 0; i4 < DD / 4; ++i4) {
        // 12 lane-coalesced W loads (3 segs x 4 rows of W)
        float w00 = W0[(i4 * 4 + 0) * HH + lane];
        float w01 = W0[(i4 * 4 + 1) * HH + lane];
        float w02 = W0[(i4 * 4 + 2) * HH + lane];
        float w03 = W0[(i4 * 4 + 3) * HH + lane];
        float w10 = W1[(i4 * 4 + 0) * HH + lane];
        float w11 = W1[(i4 * 4 + 1) * HH + lane];
        float w12 = W1[(i4 * 4 + 2) * HH + lane];
        float w13 = W1[(i4 * 4 + 3) * HH + lane];
        float w20 = W2[(i4 * 4 + 0) * HH + lane];
        float w21 = W2[(i4 * 4 + 1) * HH + lane];
        float w22 = W2[(i4 * 4 + 2) * HH + lane];
        float w23 = W2[(i4 * 4 + 3) * HH + lane];
#pragma unroll
        for (int r = 0; r < 8; ++r) {
            // wave-uniform address -> scalar broadcast, no LDS
            float4 xv = *(const float4*)(xw + r * DD + i4 * 4);
            a0[r] = fmaf(xv.x, w00, a0[r]);
            a0[r] = fmaf(xv.y, w01, a0[r]);
            a0[r] = fmaf(xv.z, w02, a0[r]);
            a0[r] = fmaf(xv.w, w03, a0[r]);
            a1[r] = fmaf(xv.x, w10, a1[r]);
            a1[r] = fmaf(xv.y, w11, a1[r]);
            a1[r] = fmaf(xv.z, w12, a1[r]);
            a1[r] = fmaf(xv.w, w13, a1[r]);
            a2[r] = fmaf(xv.x, w20, a2[r]);
            a2[r] = fmaf(xv.y, w21, a2[r]);
            a2[r] = fmaf(xv.z, w22, a2[r]);
            a2[r] = fmaf(xv.w, w23, a2[r]);
        }
    }
    float* o0 = ws + (size_t)r0 * HH + lane;
    float* o1 = ws + (size_t)NN * HH + (size_t)r0 * HH + lane;
    float* o2 = ws + 2 * (size_t)NN * HH + (size_t)r0 * HH + lane;
#pragma unroll
    for (int r = 0; r < 8; ++r) {
        o0[r * HH] = a0[r];
        o1[r * HH] = a1[r];
        o2[r * HH] = a2[r];
    }
}

// ---------------------------------------------------------------------------
// kE: thread-per-edge (exact R0 version — measured 93 us, VALUBusy 58%).
// acc[64] AGPR-backed, ew2 rows WAVE-UNIFORM -> s_load scalar path (this is
// the critical property: R1/R2's lane-dependent j-split turned 512 weight
// reads/thread into VMEM vector loads -> VALUBusy 8%, 721-849 us).
// XA/XB float4 gather with next-iteration prefetch.
// ---------------------------------------------------------------------------
__global__ __launch_bounds__(128, 4) void kE(const int* __restrict__ srcIdx,
                                             const float* __restrict__ dist,
                                             const float* __restrict__ ws,
                                             const float* __restrict__ ew1,
                                             const float* __restrict__ eb1,
                                             const float* __restrict__ ew2,
                                             const float* __restrict__ eb2,
                                             const float* __restrict__ ew3,
                                             const float* __restrict__ eb3,
                                             float* __restrict__ energy_out) {
    int e = blockIdx.x * 128 + threadIdx.x;
    if (e >= NKE) return;
    int s = srcIdx[e];
    int d = e / KK;
    float dd = dist[e];
    const float* A = ws + (size_t)d * HH;
    const float* B = ws + (size_t)NN * HH + (size_t)s * HH;
    const float* w1l = ew1 + 2 * DD * HH;

    float acc[HH];
#pragma unroll
    for (int j = 0; j < HH; ++j) acc[j] = 0.f;

    float4 a4 = *(const float4*)A;
    float4 b4 = *(const float4*)B;
#pragma unroll 1
    for (int i4 = 0; i4 < HH / 4; ++i4) {
        float4 a = a4, b = b4;
        int nx = (i4 + 1 < HH / 4) ? (i4 + 1) : i4;
        a4 = *(const float4*)(A + nx * 4);
        b4 = *(const float4*)(B + nx * 4);
        float h[4];
        h[0] = fmaxf(a.x + b.x + dd * w1l[i4 * 4 + 0] + eb1[i4 * 4 + 0], 0.f);
        h[1] = fmaxf(a.y + b.y + dd * w1l[i4 * 4 + 1] + eb1[i4 * 4 + 1], 0.f);
        h[2] = fmaxf(a.z + b.z + dd * w1l[i4 * 4 + 2] + eb1[i4 * 4 + 2], 0.f);
        h[3] = fmaxf(a.w + b.w + dd * w1l[i4 * 4 + 3] + eb1[i4 * 4 + 3], 0.f);
#pragma unroll
        for (int k = 0; k < 4; ++k) {
            const float* wr = ew2 + (i4 * 4 + k) * HH;   // wave-uniform!
#pragma unroll
            for (int j4 = 0; j4 < 16; ++j4) {
                float4 w = *(const float4*)(wr + j4 * 4);
                acc[j4 * 4 + 0] = fmaf(h[k], w.x, acc[j4 * 4 + 0]);
                acc[j4 * 4 + 1] = fmaf(h[k], w.y, acc[j4 * 4 + 1]);
                acc[j4 * 4 + 2] = fmaf(h[k], w.z, acc[j4 * 4 + 2]);
                acc[j4 * 4 + 3] = fmaf(h[k], w.w, acc[j4 * 4 + 3]);
            }
        }
    }
    float lg = eb3[0];
#pragma unroll
    for (int j = 0; j < HH; ++j)
        lg = fmaf(fmaxf(acc[j] + eb2[j], 0.f), ew3[j], lg);
    energy_out[e] = 1.f / (1.f + expf(-2.f * lg));
}

// ---------------------------------------------------------------------------
// kF: FOUR threads per node (lanes 4n..4n+3), each owns 16 of 64 hidden-j.
// 200k threads = 12 waves/CU (was 3), acc[16]/thread.  Passed correctness in
// R1+R2.  NOTE: dw2 access here is lane-dependent (p*16) — same VMEM-vs-
// scalar issue as kE's failed split, but kF is tiny (1/15 the edges' work)
// and was latency-starved on occupancy, so net effect expected positive;
// R3 measures it indirectly via total - kE - kP.
// ---------------------------------------------------------------------------
__global__ __launch_bounds__(256, 3) void kF(const float* __restrict__ ws,
                                             const float* __restrict__ dw1,
                                             const float* __restrict__ db1,
                                             const float* __restrict__ dw2,
                                             const float* __restrict__ db2,
                                             const float* __restrict__ dw3,
                                             const float* __restrict__ db3,
                                             float* __restrict__ out) {
    int t = blockIdx.x * 256 + threadIdx.x;
    int n = t >> 2;
    int p = t & 3;
    if (n >= NN) return;
    const float* energy = out + 2 * (size_t)NKE;

    float ev[KK];
    float dh = 0.f;
#pragma unroll
    for (int j = 0; j < KK; ++j) {
        ev[j] = energy[(size_t)n * KK + j];
        dh += ev[j];
    }

    const float* XC = ws + 2 * (size_t)NN * HH + (size_t)n * HH;
    const float* w1l = dw1 + DD * HH;
    const float* W2 = dw2 + p * 16;             // this thread's 16-col slice

    float acc[16];
#pragma unroll
    for (int j = 0; j < 16; ++j) acc[j] = 0.f;

    float4 c4 = *(const float4*)XC;
#pragma unroll 1
    for (int i4 = 0; i4 < HH / 4; ++i4) {
        float4 c = c4;
        int nx = (i4 + 1 < HH / 4) ? (i4 + 1) : i4;
        c4 = *(const float4*)(XC + nx * 4);
        float cv[4] = {c.x, c.y, c.z, c.w};
#pragma unroll
        for (int m = 0; m < 4; ++m) {
            int k = i4 * 4 + m;
            float g = fmaxf(cv[m] + dh * w1l[k] + db1[k], 0.f);
            const float* wr = W2 + k * HH;
#pragma unroll
            for (int j4 = 0; j4 < 4; ++j4) {
                float4 w = *(const float4*)(wr + j4 * 4);
                acc[j4 * 4 + 0] = fmaf(g, w.x, acc[j4 * 4 + 0]);
                acc[j4 * 4 + 1] = fmaf(g, w.y, acc[j4 * 4 + 1]);
                acc[j4 * 4 + 2] = fmaf(g, w.z, acc[j4 * 4 + 2]);
                acc[j4 * 4 + 3] = fmaf(g, w.w, acc[j4 * 4 + 3]);
            }
        }
    }
    float kp_ = 0.f;
#pragma unroll
    for (int j = 0; j < 16; ++j)
        kp_ = fmaf(fmaxf(acc[j] + db2[p * 16 + j], 0.f), dw3[p * 16 + j], kp_);
    kp_ += __shfl_xor(kp_, 1);
    kp_ += __shfl_xor(kp_, 2);                  // all 4 lanes hold full kraw
    float kraw = kp_ + db3[0];

    float kcont = 2.f + 13.f / (1.f + expf(-kraw));
    if (p == 3) out[3 * (size_t)NKE + n] = kcont;

    // register-resident sort of (energy desc, idx asc), 16-wide network
    float se[16];
    int si[16];
#pragma unroll
    for (int j = 0; j < KK; ++j) { se[j] = ev[j]; si[j] = j; }
    se[15] = -1.f; si[15] = 15;

#pragma unroll
    for (int pp = 1; pp < 16; pp <<= 1) {
#pragma unroll
        for (int k = pp; k >= 1; k >>= 1) {
#pragma unroll
            for (int j = k & (pp - 1); j + k < 16; j += 2 * k) {
#pragma unroll
                for (int i = 0; i < k; ++i) {
                    int a = i + j, b = i + j + k;
                    if (b < 16 && (a / (2 * pp)) == (b / (2 * pp))) {
                        bool sw = (se[b] > se[a]) ||
                                  (se[b] == se[a] && si[b] < si[a]);
                        float ea = sw ? se[b] : se[a];
                        float eb = sw ? se[a] : se[b];
                        int ia = sw ? si[b] : si[a];
                        int ib = sw ? si[a] : si[b];
                        se[a] = ea; se[b] = eb; si[a] = ia; si[b] = ib;
                    }
                }
            }
        }
    }

    float kint = rintf(kcont);
    kint = fminf(fmaxf(kint, 2.f), 15.f);

    float wsrt[KK];
    float denom = 0.f;
#pragma unroll
    for (int r = 0; r < KK; ++r) {
        float sel = ((float)(r + 1) <= kint) ? 1.f : 0.f;
        float wvv = se[r] * sel;
        wsrt[r] = wvv;
        denom += wvv;
    }
    denom = fmaxf(denom, 1e-12f);

#pragma unroll
    for (int r = 0; r < KK; ++r) {
        if ((r & 3) == p) {                     // stripe writes across the 4 lanes
            float sel = ((float)(r + 1) <= kint) ? 1.f : 0.f;
            int j0 = si[r];
            out[(size_t)NKE + (size_t)n * KK + j0] = sel;     // edge_gate
            out[(size_t)n * KK + j0] = wsrt[r] / denom;       // edge_weight
        }
    }
}

extern "C" void kernel_launch(void* const* d_in, const int* in_sizes, int n_in,
                              void* d_out, int out_size, void* d_ws, size_t ws_size,
                              hipStream_t stream) {
    const float* x   = (const float*)d_in[0];
    const int*   ei  = (const int*)d_in[1];
    const float* ed  = (const float*)d_in[2];
    const float* ew1 = (const float*)d_in[3];
    const float* eb1 = (const float*)d_in[4];
    const float* ew2 = (const float*)d_in[5];
    const float* eb2 = (const float*)d_in[6];
    const float* ew3 = (const float*)d_in[7];
    const float* eb3 = (const float*)d_in[8];
    const float* dw1 = (const float*)d_in[9];
    const float* db1 = (const float*)d_in[10];
    const float* dw2 = (const float*)d_in[11];
    const float* db2 = (const float*)d_in[12];
    const float* dw3 = (const float*)d_in[13];
    const float* db3 = (const float*)d_in[14];
    float* out = (float*)d_out;
    float* ws  = (float*)d_ws;

    hipLaunchKernelGGL(kP, dim3((NN + 31) / 32), dim3(256), 0, stream,
                       x, ew1, dw1, ws);
    hipLaunchKernelGGL(kE, dim3((NKE + 127) / 128), dim3(128), 0, stream,
                       ei, ed, ws, ew1, eb1, ew2, eb2, ew3, eb3,
                       out + 2 * (size_t)NKE);
    hipLaunchKernelGGL(kF, dim3((4 * NN + 255) / 256), dim3(256), 0, stream,
                       ws, dw1, db1, dw2, db2, dw3, db3, out);
}

// Round 4
// 291.472 us; speedup vs baseline: 3.2292x; 1.0511x over previous
//
#include <hip/hip_runtime.h>
#include <cmath>

#define NN 50000
#define KK 15
#define DD 128
#define HH 64
#define NKE (NN * KK)

// ---------------------------------------------------------------------------
// kP: fused 3-segment per-node GEMM, NO LDS.  (R0 version, verified ~90 us.)
//   ws[0][row][j] = x[row] @ ew1[0:128]      (XA)
//   ws[1][row][j] = x[row] @ ew1[128:256]    (XB)
//   ws[2][row][j] = x[row] @ dw1[0:128]      (XC)
// R1 lesson: no register ping-pong buffers here (spill storm, 41 ms).
// ---------------------------------------------------------------------------
__global__ __launch_bounds__(256) void kP(const float* __restrict__ x,
                                          const float* __restrict__ ew1,
                                          const float* __restrict__ dw1,
                                          float* __restrict__ ws) {
    int lane = threadIdx.x & 63;
    int wv = __builtin_amdgcn_readfirstlane((int)(threadIdx.x >> 6));
    int r0 = blockIdx.x * 32 + wv * 8;       // 50000 % 8 == 0: no intra-wave tail
    if (r0 >= NN) return;

    const float* W0 = ew1;
    const float* W1 = ew1 + DD * HH;
    const float* W2 = dw1;
    const float* xw = x + (size_t)r0 * DD;

    float a0[8], a1[8], a2[8];
#pragma unroll
    for (int r = 0; r < 8; ++r) { a0[r] = 0.f; a1[r] = 0.f; a2[r] = 0.f; }

#pragma unroll 1
    for (int i4 = 0; i4 < DD / 4; ++i4) {
        float w00 = W0[(i4 * 4 + 0) * HH + lane];
        float w01 = W0[(i4 * 4 + 1) * HH + lane];
        float w02 = W0[(i4 * 4 + 2) * HH + lane];
        float w03 = W0[(i4 * 4 + 3) * HH + lane];
        float w10 = W1[(i4 * 4 + 0) * HH + lane];
        float w11 = W1[(i4 * 4 + 1) * HH + lane];
        float w12 = W1[(i4 * 4 + 2) * HH + lane];
        float w13 = W1[(i4 * 4 + 3) * HH + lane];
        float w20 = W2[(i4 * 4 + 0) * HH + lane];
        float w21 = W2[(i4 * 4 + 1) * HH + lane];
        float w22 = W2[(i4 * 4 + 2) * HH + lane];
        float w23 = W2[(i4 * 4 + 3) * HH + lane];
#pragma unroll
        for (int r = 0; r < 8; ++r) {
            // wave-uniform address -> scalar broadcast, no LDS
            float4 xv = *(const float4*)(xw + r * DD + i4 * 4);
            a0[r] = fmaf(xv.x, w00, a0[r]);
            a0[r] = fmaf(xv.y, w01, a0[r]);
            a0[r] = fmaf(xv.z, w02, a0[r]);
            a0[r] = fmaf(xv.w, w03, a0[r]);
            a1[r] = fmaf(xv.x, w10, a1[r]);
            a1[r] = fmaf(xv.y, w11, a1[r]);
            a1[r] = fmaf(xv.z, w12, a1[r]);
            a1[r] = fmaf(xv.w, w13, a1[r]);
            a2[r] = fmaf(xv.x, w20, a2[r]);
            a2[r] = fmaf(xv.y, w21, a2[r]);
            a2[r] = fmaf(xv.z, w22, a2[r]);
            a2[r] = fmaf(xv.w, w23, a2[r]);
        }
    }
    float* o0 = ws + (size_t)r0 * HH + lane;
    float* o1 = ws + (size_t)NN * HH + (size_t)r0 * HH + lane;
    float* o2 = ws + 2 * (size_t)NN * HH + (size_t)r0 * HH + lane;
#pragma unroll
    for (int r = 0; r < 8; ++r) {
        o0[r * HH] = a0[r];
        o1[r * HH] = a1[r];
        o2[r * HH] = a2[r];
    }
}

// ---------------------------------------------------------------------------
// kE: WAVE-split j.  Block = 2 waves <-> 64 edges; wave wv owns j-columns
// [wv*32, wv*32+32).  W2 = ew2 + wv*32 is WAVE-UNIFORM (readfirstlane) ->
// scalar s_load path preserved (R1/R2 lesson: lane-dependent weight slices
// become per-lane VMEM -> 8% VALUBusy).  acc[32] halves register state vs
// R0's acc[64] -> ~7 waves/SIMD (was 3.6 at 45% occupancy).  lg halves
// reduced via 512B LDS; wave 0 stores.  A/B gathers duplicated across the
// wave pair but hit L1 (same CU, same 16KB working set).
// ---------------------------------------------------------------------------
__global__ __launch_bounds__(128, 4) void kE(const int* __restrict__ srcIdx,
                                             const float* __restrict__ dist,
                                             const float* __restrict__ ws,
                                             const float* __restrict__ ew1,
                                             const float* __restrict__ eb1,
                                             const float* __restrict__ ew2,
                                             const float* __restrict__ eb2,
                                             const float* __restrict__ ew3,
                                             const float* __restrict__ eb3,
                                             float* __restrict__ energy_out) {
    int lane = threadIdx.x & 63;
    int wv = __builtin_amdgcn_readfirstlane((int)(threadIdx.x >> 6));  // 0..1
    int e = blockIdx.x * 64 + lane;
    __shared__ float lred[2][64];

    bool valid = e < NKE;
    int ec = valid ? e : (NKE - 1);            // clamp: no early return (barrier!)
    int s = srcIdx[ec];
    int d = ec / KK;
    float dd = dist[ec];
    const float* A = ws + (size_t)d * HH;
    const float* B = ws + (size_t)NN * HH + (size_t)s * HH;
    const float* w1l = ew1 + 2 * DD * HH;
    const float* W2  = ew2 + wv * 32;          // wave-uniform col slice
    const float* eb2s = eb2 + wv * 32;
    const float* ew3s = ew3 + wv * 32;

    float acc[32];
#pragma unroll
    for (int j = 0; j < 32; ++j) acc[j] = 0.f;

    float4 a4 = *(const float4*)A;
    float4 b4 = *(const float4*)B;
#pragma unroll 1
    for (int i4 = 0; i4 < HH / 4; ++i4) {
        float4 a = a4, b = b4;
        int nx = (i4 + 1 < HH / 4) ? (i4 + 1) : i4;
        a4 = *(const float4*)(A + nx * 4);
        b4 = *(const float4*)(B + nx * 4);
        float h[4];
        h[0] = fmaxf(a.x + b.x + dd * w1l[i4 * 4 + 0] + eb1[i4 * 4 + 0], 0.f);
        h[1] = fmaxf(a.y + b.y + dd * w1l[i4 * 4 + 1] + eb1[i4 * 4 + 1], 0.f);
        h[2] = fmaxf(a.z + b.z + dd * w1l[i4 * 4 + 2] + eb1[i4 * 4 + 2], 0.f);
        h[3] = fmaxf(a.w + b.w + dd * w1l[i4 * 4 + 3] + eb1[i4 * 4 + 3], 0.f);
#pragma unroll
        for (int k = 0; k < 4; ++k) {
            const float* wr = W2 + (i4 * 4 + k) * HH;   // wave-uniform row
#pragma unroll
            for (int j4 = 0; j4 < 8; ++j4) {
                float4 w = *(const float4*)(wr + j4 * 4);
                acc[j4 * 4 + 0] = fmaf(h[k], w.x, acc[j4 * 4 + 0]);
                acc[j4 * 4 + 1] = fmaf(h[k], w.y, acc[j4 * 4 + 1]);
                acc[j4 * 4 + 2] = fmaf(h[k], w.z, acc[j4 * 4 + 2]);
                acc[j4 * 4 + 3] = fmaf(h[k], w.w, acc[j4 * 4 + 3]);
            }
        }
    }
    float lg = 0.f;
#pragma unroll
    for (int j = 0; j < 32; ++j)
        lg = fmaf(fmaxf(acc[j] + eb2s[j], 0.f), ew3s[j], lg);

    lred[wv][lane] = lg;
    __syncthreads();
    if (wv == 0 && valid) {
        float t = lred[0][lane] + lred[1][lane] + eb3[0];
        energy_out[e] = 1.f / (1.f + expf(-2.f * t));
    }
}

// ---------------------------------------------------------------------------
// kF: WAVE-split j.  Block = 4 waves <-> 64 nodes; wave wv owns j-columns
// [wv*16, wv*16+16) -> dw2 + wv*16 WAVE-UNIFORM (scalar path; R3's lane-
// split p*16 was per-lane VMEM -> 103 us, 25% VALUBusy).  acc[16]; kraw
// reduced via 1KB LDS (2-way bank access = free); sort duplicated per wave
// (identical in-register result, all lanes busy), scatter writes striped by
// rank&3 == wv.  200k threads = 12 waves/CU vs old kF's 3.
// ---------------------------------------------------------------------------
__global__ __launch_bounds__(256, 2) void kF(const float* __restrict__ ws,
                                             const float* __restrict__ dw1,
                                             const float* __restrict__ db1,
                                             const float* __restrict__ dw2,
                                             const float* __restrict__ db2,
                                             const float* __restrict__ dw3,
                                             const float* __restrict__ db3,
                                             float* __restrict__ out) {
    int lane = threadIdx.x & 63;
    int wv = __builtin_amdgcn_readfirstlane((int)(threadIdx.x >> 6));  // 0..3
    int n = blockIdx.x * 64 + lane;
    __shared__ float kred[4][64];

    bool valid = n < NN;
    int nc = valid ? n : (NN - 1);             // clamp: no early return (barrier!)
    const float* energy = out + 2 * (size_t)NKE;

    float ev[KK];
    float dh = 0.f;
#pragma unroll
    for (int j = 0; j < KK; ++j) {
        ev[j] = energy[(size_t)nc * KK + j];
        dh += ev[j];
    }

    const float* XC  = ws + 2 * (size_t)NN * HH + (size_t)nc * HH;
    const float* w1l = dw1 + DD * HH;
    const float* W2  = dw2 + wv * 16;          // wave-uniform col slice
    const float* db2s = db2 + wv * 16;
    const float* dw3s = dw3 + wv * 16;

    float acc[16];
#pragma unroll
    for (int j = 0; j < 16; ++j) acc[j] = 0.f;

    float4 c4 = *(const float4*)XC;
#pragma unroll 1
    for (int i4 = 0; i4 < HH / 4; ++i4) {
        float4 c = c4;
        int nx = (i4 + 1 < HH / 4) ? (i4 + 1) : i4;
        c4 = *(const float4*)(XC + nx * 4);
        float cv[4] = {c.x, c.y, c.z, c.w};
#pragma unroll
        for (int m = 0; m < 4; ++m) {
            int k = i4 * 4 + m;
            float g = fmaxf(cv[m] + dh * w1l[k] + db1[k], 0.f);
            const float* wr = W2 + k * HH;     // wave-uniform row
#pragma unroll
            for (int j4 = 0; j4 < 4; ++j4) {
                float4 w = *(const float4*)(wr + j4 * 4);
                acc[j4 * 4 + 0] = fmaf(g, w.x, acc[j4 * 4 + 0]);
                acc[j4 * 4 + 1] = fmaf(g, w.y, acc[j4 * 4 + 1]);
                acc[j4 * 4 + 2] = fmaf(g, w.z, acc[j4 * 4 + 2]);
                acc[j4 * 4 + 3] = fmaf(g, w.w, acc[j4 * 4 + 3]);
            }
        }
    }
    float kp_ = 0.f;
#pragma unroll
    for (int j = 0; j < 16; ++j)
        kp_ = fmaf(fmaxf(acc[j] + db2s[j], 0.f), dw3s[j], kp_);

    kred[wv][lane] = kp_;
    __syncthreads();
    float kraw = kred[0][lane] + kred[1][lane] + kred[2][lane] + kred[3][lane]
               + db3[0];
    if (!valid) return;

    float kcont = 2.f + 13.f / (1.f + expf(-kraw));
    if (wv == 3) out[3 * (size_t)NKE + n] = kcont;

    // register-resident sort of (energy desc, idx asc), 16-wide network
    // (duplicated in all 4 waves — identical result, keeps lanes busy)
    float se[16];
    int si[16];
#pragma unroll
    for (int j = 0; j < KK; ++j) { se[j] = ev[j]; si[j] = j; }
    se[15] = -1.f; si[15] = 15;

#pragma unroll
    for (int pp = 1; pp < 16; pp <<= 1) {
#pragma unroll
        for (int k = pp; k >= 1; k >>= 1) {
#pragma unroll
            for (int j = k & (pp - 1); j + k < 16; j += 2 * k) {
#pragma unroll
                for (int i = 0; i < k; ++i) {
                    int a = i + j, b = i + j + k;
                    if (b < 16 && (a / (2 * pp)) == (b / (2 * pp))) {
                        bool sw = (se[b] > se[a]) ||
                                  (se[b] == se[a] && si[b] < si[a]);
                        float ea = sw ? se[b] : se[a];
                        float eb = sw ? se[a] : se[b];
                        int ia = sw ? si[b] : si[a];
                        int ib = sw ? si[a] : si[b];
                        se[a] = ea; se[b] = eb; si[a] = ia; si[b] = ib;
                    }
                }
            }
        }
    }

    float kint = rintf(kcont);
    kint = fminf(fmaxf(kint, 2.f), 15.f);

    float wsrt[KK];
    float denom = 0.f;
#pragma unroll
    for (int r = 0; r < KK; ++r) {
        float sel = ((float)(r + 1) <= kint) ? 1.f : 0.f;
        float wvv = se[r] * sel;
        wsrt[r] = wvv;
        denom += wvv;
    }
    denom = fmaxf(denom, 1e-12f);

#pragma unroll
    for (int r = 0; r < KK; ++r) {
        if ((r & 3) == wv) {                   // stripe writes across the 4 waves
            float sel = ((float)(r + 1) <= kint) ? 1.f : 0.f;
            int j0 = si[r];
            out[(size_t)NKE + (size_t)n * KK + j0] = sel;     // edge_gate
            out[(size_t)n * KK + j0] = wsrt[r] / denom;       // edge_weight
        }
    }
}

extern "C" void kernel_launch(void* const* d_in, const int* in_sizes, int n_in,
                              void* d_out, int out_size, void* d_ws, size_t ws_size,
                              hipStream_t stream) {
    const float* x   = (const float*)d_in[0];
    const int*   ei  = (const int*)d_in[1];
    const float* ed  = (const float*)d_in[2];
    const float* ew1 = (const float*)d_in[3];
    const float* eb1 = (const float*)d_in[4];
    const float* ew2 = (const float*)d_in[5];
    const float* eb2 = (const float*)d_in[6];
    const float* ew3 = (const float*)d_in[7];
    const float* eb3 = (const float*)d_in[8];
    const float* dw1 = (const float*)d_in[9];
    const float* db1 = (const float*)d_in[10];
    const float* dw2 = (const float*)d_in[11];
    const float* db2 = (const float*)d_in[12];
    const float* dw3 = (const float*)d_in[13];
    const float* db3 = (const float*)d_in[14];
    float* out = (float*)d_out;
    float* ws  = (float*)d_ws;

    hipLaunchKernelGGL(kP, dim3((NN + 31) / 32), dim3(256), 0, stream,
                       x, ew1, dw1, ws);
    hipLaunchKernelGGL(kE, dim3((NKE + 63) / 64), dim3(128), 0, stream,
                       ei, ed, ws, ew1, eb1, ew2, eb2, ew3, eb3,
                       out + 2 * (size_t)NKE);
    hipLaunchKernelGGL(kF, dim3((NN + 63) / 64), dim3(256), 0, stream,
                       ws, dw1, db1, dw2, db2, dw3, db3, out);
}